// Round 6
// baseline (145.054 us; speedup 1.0000x reference)
//
#include <hip/hip_runtime.h>
#include <math.h>

#define BATCH 4
#define SEQT  4096
#define CDIM  512
#define HDIM  64

typedef unsigned short ushort_t;
typedef __attribute__((ext_vector_type(8))) short bf16x8;
typedef __attribute__((ext_vector_type(4))) float f32x4;

#define MFMA16(a, b, c) __builtin_amdgcn_mfma_f32_16x16x32_bf16((a), (b), (c), 0, 0, 0)
#define NEG (-1e30f)

// Compiler-only memory fence (keeps the uint2-write/bf16x8-read LDS
// round-trip ordered at IR level regardless of TBAA; free at runtime).
#define MEMFENCE() asm volatile("" ::: "memory")

__device__ __forceinline__ ushort_t f2bf(float f) {
  union { float f; unsigned int u; } v;
  v.f = f;
  unsigned int u = v.u;
  u += 0x7fffu + ((u >> 16) & 1u);  // round-to-nearest-even
  return (ushort_t)(u >> 16);
}

// Raw v_exp_f32 (= exp2). log2(e) is folded into the Wq scale so the
// attention softmax needs no per-element multiply before the exp.
__device__ __forceinline__ float fexp2(float x) {
#if __has_builtin(__builtin_amdgcn_exp2f)
  return __builtin_amdgcn_exp2f(x);
#else
  float r;
  asm("v_exp_f32 %0, %1" : "=v"(r) : "v"(x));
  return r;
#endif
}
// Packed f32x2 -> bf16x2 (RNE, lo=arg0 hi=arg1). No builtin on gfx950 -> asm.
__device__ __forceinline__ unsigned int cvtpk(float lo, float hi) {
  unsigned int r;
  asm("v_cvt_pk_bf16_f32 %0, %1, %2" : "=v"(r) : "v"(lo), "v"(hi));
  return r;
}

// ---------------------------------------------------------------------------
// Kernel 0: W[c][h] fp32 -> wtf in MFMA B-fragment order:
//   wtf[((mat*16 + ks)*4 + nt)*512 + lane*8 + j] = W[(ks*32+quad*8+j)*64 + nt*16+n]
// Scale log2(e)/sqrt(512) folded into Wq (attn uses exp2).
// ---------------------------------------------------------------------------
__global__ __launch_bounds__(256) void convert_w(
    const float* __restrict__ Wq, const float* __restrict__ Wk,
    const float* __restrict__ Wv, ushort_t* __restrict__ wtf) {
  int g = blockIdx.x * 256 + threadIdx.x;  // 0 .. 12287
  int lane = g & 63;
  int nt = (g >> 6) & 3;
  int ks = (g >> 8) & 15;
  int mat = g >> 12;
  const float* W = (mat == 0) ? Wq : (mat == 1) ? Wk : Wv;
  // 1/sqrt(512) * log2(e) = 0.06375871540857175
  const float sc = (mat == 0) ? 0.06375871540857175f : 1.0f;
  int n = lane & 15, quad = lane >> 4;
  int h = nt * 16 + n;
  int c0 = ks * 32 + quad * 8;
  ushort_t tmp[8];
#pragma unroll
  for (int j = 0; j < 8; ++j) tmp[j] = f2bf(W[(c0 + j) * HDIM + h] * sc);
  *(bf16x8*)(wtf + (size_t)g * 8) = *(const bf16x8*)tmp;
}

// ---------------------------------------------------------------------------
// Kernel 1: QKV projection. 32 rows/block, 384 threads = 6 waves:
// wave w -> matrix w>>1, row-half w&1. Double-buffered B-frag loads.
// Staging uses v_cvt_pk_bf16_f32 (1 inst / 2 elems, same RNE as f2bf).
// Outputs: qb row-major bf16; kbf / vbf in MFMA fragment order.
// ---------------------------------------------------------------------------
#define XPAD 520  // shorts; odd-dword stride (260) -> conflict-light

__global__ __launch_bounds__(384) void qkv_proj(
    const float* __restrict__ x, const ushort_t* __restrict__ wtf,
    ushort_t* __restrict__ qb, ushort_t* __restrict__ kbf,
    ushort_t* __restrict__ vbf) {
  __shared__ ushort_t Xs[32 * XPAD];   // 33.3 KB
  __shared__ ushort_t Pk[3][32 * 72];  // 13.8 KB

  const int tid = threadIdx.x;
  const int row0 = blockIdx.x * 32;  // global row = b*4096 + t

  // Stage X tile fp32 -> bf16 (cvt_pk + packed 8B LDS writes).
  const float4* xg = (const float4*)(x + (size_t)row0 * CDIM);
  for (int i = tid; i < 32 * (CDIM / 4); i += 384) {
    float4 xv = xg[i];
    int r = i >> 7, c4 = i & 127;
    uint2 u;
    u.x = cvtpk(xv.x, xv.y);
    u.y = cvtpk(xv.z, xv.w);
    *(uint2*)&Xs[r * XPAD + c4 * 4] = u;
  }
  __syncthreads();

  const int lane = tid & 63;
  const int w = tid >> 6;      // 0..5
  const int mat = w >> 1;      // 0=q 1=k 2=v
  const int half = w & 1;      // row half (16 rows each)
  const int n = lane & 15, quad = lane >> 4;
  const ushort_t* wb = wtf + mat * 32768;

  f32x4 acc[4];
#pragma unroll
  for (int nt = 0; nt < 4; ++nt) acc[nt] = (f32x4){0.f, 0.f, 0.f, 0.f};

  // Software-pipelined B-frag loads (hide L2 latency behind MFMAs).
  bf16x8 bcur[4];
#pragma unroll
  for (int nt = 0; nt < 4; ++nt)
    bcur[nt] = *(const bf16x8*)&wb[nt * 512 + lane * 8];

  for (int ks = 0; ks < 16; ++ks) {
    bf16x8 a = *(const bf16x8*)&Xs[(half * 16 + n) * XPAD + ks * 32 + quad * 8];
    bf16x8 bnext[4];
    if (ks < 15) {
#pragma unroll
      for (int nt = 0; nt < 4; ++nt)
        bnext[nt] = *(const bf16x8*)&wb[((ks + 1) * 4 + nt) * 512 + lane * 8];
    }
#pragma unroll
    for (int nt = 0; nt < 4; ++nt) acc[nt] = MFMA16(a, bcur[nt], acc[nt]);
    if (ks < 15) {
#pragma unroll
      for (int nt = 0; nt < 4; ++nt) bcur[nt] = bnext[nt];
    }
  }

  // C/D -> row-major bf16 in LDS.
  ushort_t* P = Pk[mat];
#pragma unroll
  for (int nt = 0; nt < 4; ++nt)
#pragma unroll
    for (int i = 0; i < 4; ++i)
      P[(half * 16 + quad * 4 + i) * 72 + nt * 16 + n] = f2bf(acc[nt][i]);
  __syncthreads();

  if (mat == 0) {
    // qb rows row0..row0+31; 128 chunks of 32 B over 2 waves.
    int c = half * 64 + lane;
    int r = c >> 2, seg = c & 3;
    const uint4* s = (const uint4*)&Pk[0][r * 72 + seg * 16];
    uint4* d = (uint4*)(qb + (size_t)(row0 + r) * HDIM + seg * 16);
    d[0] = s[0];
    d[1] = s[1];
  } else if (mat == 1) {
    // K fragments: group (row0>>4)+half, frags ks=0,1.
#pragma unroll
    for (int ks2 = 0; ks2 < 2; ++ks2) {
      bf16x8 fr =
          *(const bf16x8*)&Pk[1][(half * 16 + n) * 72 + ks2 * 32 + quad * 8];
      *(bf16x8*)(kbf + (size_t)(((row0 >> 4) + half) * 2 + ks2) * 512 +
                 lane * 8) = fr;
    }
  } else {
    // V^T fragments (in-LDS transpose); wave half emits nt = 2*half, 2*half+1.
    const int b = row0 >> 12, t0 = row0 & 4095;
    const int kt = t0 >> 6, kslot = (t0 >> 5) & 1;
#pragma unroll
    for (int ntc = 0; ntc < 2; ++ntc) {
      const int nt = half * 2 + ntc;
      ushort_t tmp[8];
#pragma unroll
      for (int j = 0; j < 8; ++j)
        tmp[j] = Pk[2][(quad * 8 + j) * 72 + nt * 16 + n];
      *(bf16x8*)(vbf + (size_t)(((b * 64 + kt) * 4 + nt) * 2 + kslot) * 512 +
                 lane * 8) = *(const bf16x8*)tmp;
    }
  }
}

// ---------------------------------------------------------------------------
// Kernel 2: causal flash attention — R1 STRUCTURE (one block per (b,qt),
// grid 512, heavy-first, in-LDS 8-wave merge, direct normalized output; the
// 111.6us verified baseline). R5's k-split regressed the bench (+25us) from
// partial-buffer traffic + extra kernel, so it is reverted. Changes here:
//  * V-LOAD HOIST: all 8 V-frag loads issued at the top of each k-iter so
//    their L2 latency hides under QK^T+mask+exp+LDS instead of sitting
//    exposed before the PV MFMAs (the MEMFENCE blocks compiler hoisting;
//    tested in isolation here — R2 bundled it with the broken hh-loop).
//  * T5 setprio(1/0) around the QK^T and PV MFMA clusters (independent
//    waves; the regime where attn measured +4-7%).
// ---------------------------------------------------------------------------
__global__ __launch_bounds__(512, 4) void attn(
    const ushort_t* __restrict__ qb, const ushort_t* __restrict__ kbf,
    const ushort_t* __restrict__ vbf, float* __restrict__ out) {
  // Union: Ps [8][32*72] shorts (36864 B) during k-loop;
  //        Om [8][32*68] floats (69632 B) + Ol [8][32] floats at merge.
  __shared__ __align__(16) char smem[70656];
  ushort_t* Ps = (ushort_t*)smem;
  float* Om = (float*)smem;
  float* Ol = (float*)(smem + 69632);

  const int tid = threadIdx.x;
  const int lane = tid & 63;
  const int w = tid >> 6;  // 0..7
  const int n = lane & 15, quad = lane >> 4;

  const int b = blockIdx.x & 3;
  const int qt = 127 - (blockIdx.x >> 2);  // heavy-first
  const int q0 = qt * 32;

  const ushort_t* qB = qb + (size_t)b * SEQT * HDIM;
  const ushort_t* kB = kbf + (size_t)b * 512 * 512;
  const ushort_t* vB = vbf + (size_t)b * 512 * 512;
  float* oB = out + (size_t)b * SEQT * HDIM;

  // Q fragments, used as the B operand (col = q). Scale folded into Wq.
  bf16x8 qf[2][2];
#pragma unroll
  for (int g = 0; g < 2; ++g)
#pragma unroll
    for (int ks = 0; ks < 2; ++ks)
      qf[g][ks] = *(const bf16x8*)&qB[(size_t)(q0 + g * 16 + n) * HDIM +
                                      ks * 32 + quad * 8];

  bf16x8 ones;
#pragma unroll
  for (int j = 0; j < 8; ++j) ones[j] = (short)0x3F80;  // bf16 1.0

  // o[nt][g] holds O^T: row h = nt*16+quad*4+i, col q = g*16+n.
  f32x4 o[4][2], ol[2];
#pragma unroll
  for (int nt = 0; nt < 4; ++nt)
#pragma unroll
    for (int g = 0; g < 2; ++g) o[nt][g] = (f32x4){0.f, 0.f, 0.f, 0.f};
  ol[0] = (f32x4){0.f, 0.f, 0.f, 0.f};
  ol[1] = (f32x4){0.f, 0.f, 0.f, 0.f};

  const int ktiles = (q0 + 95) >> 6;  // ceil((q0+32)/64)
  ushort_t* Pw = Ps + w * 2304;       // wave-private [q=32][k=64+8pad] u16

  for (int kt = w; kt < ktiles; kt += 8) {
    const int k0 = kt * 64;

    // HOISTED V loads: issue first so L2 latency hides under QK^T+exp+LDS.
    bf16x8 vfr[2][4];
#pragma unroll
    for (int ks = 0; ks < 2; ++ks)
#pragma unroll
      for (int nt = 0; nt < 4; ++nt)
        vfr[ks][nt] = *(const bf16x8*)&vB[(size_t)((kt * 4 + nt) * 2 + ks) *
                                              512 +
                                          lane * 8];

    // S^T = K Q^T : C row = k (kk*16+quad*4+i), col = q (g*16+n).
    f32x4 s[4][2];
#pragma unroll
    for (int kk = 0; kk < 4; ++kk) {
      s[kk][0] = (f32x4){0.f, 0.f, 0.f, 0.f};
      s[kk][1] = (f32x4){0.f, 0.f, 0.f, 0.f};
    }
    __builtin_amdgcn_s_setprio(1);
#pragma unroll
    for (int ks = 0; ks < 2; ++ks)
#pragma unroll
      for (int kk = 0; kk < 4; ++kk) {
        bf16x8 kf = *(const bf16x8*)&kB[(size_t)((kt * 4 + kk) * 2 + ks) * 512 +
                                        lane * 8];
        s[kk][0] = MFMA16(kf, qf[0][ks], s[kk][0]);
        s[kk][1] = MFMA16(kf, qf[1][ks], s[kk][1]);
      }
    __builtin_amdgcn_s_setprio(0);

    // Causal mask (diagonal tile only): k-row > q-col.
    if (k0 + 63 > q0) {
#pragma unroll
      for (int kk = 0; kk < 4; ++kk) {
        const int krow = k0 + kk * 16 + quad * 4;
#pragma unroll
        for (int g = 0; g < 2; ++g) {
          const int qcol = q0 + g * 16 + n;
#pragma unroll
          for (int i = 0; i < 4; ++i)
            if (krow + i > qcol) s[kk][g][i] = NEG;
        }
      }
    }

    // p = exp2(s') (max-free; shift cancels in O/l). Each lane holds 4
    // consecutive k for one q-column -> 2 cvt_pk + one b64 LDS write.
#pragma unroll
    for (int kk = 0; kk < 4; ++kk)
#pragma unroll
      for (int g = 0; g < 2; ++g) {
        uint2 wv;
        wv.x = cvtpk(fexp2(s[kk][g][0]), fexp2(s[kk][g][1]));
        wv.y = cvtpk(fexp2(s[kk][g][2]), fexp2(s[kk][g][3]));
        *(uint2*)&Pw[(g * 16 + n) * 72 + kk * 16 + quad * 4] = wv;
      }

    MEMFENCE();  // pin ds_write(P) before ds_read(P)

    // O^T += V^T P^T ; l += 1^T P^T (wave-private LDS, no barrier).
    // P^T B-frag = contiguous b128 from row-major Pw[q][k].
    __builtin_amdgcn_s_setprio(1);
#pragma unroll
    for (int ks = 0; ks < 2; ++ks) {
      bf16x8 pb0 = *(const bf16x8*)&Pw[n * 72 + ks * 32 + quad * 8];
      bf16x8 pb1 = *(const bf16x8*)&Pw[(16 + n) * 72 + ks * 32 + quad * 8];
      ol[0] = MFMA16(ones, pb0, ol[0]);
      ol[1] = MFMA16(ones, pb1, ol[1]);
#pragma unroll
      for (int nt = 0; nt < 4; ++nt) {
        o[nt][0] = MFMA16(vfr[ks][nt], pb0, o[nt][0]);
        o[nt][1] = MFMA16(vfr[ks][nt], pb1, o[nt][1]);
      }
    }
    __builtin_amdgcn_s_setprio(0);

    MEMFENCE();  // pin this tile's P-reads before next tile's P-writes
  }

  // ---- Additive merge of 8 waves. ----
  __syncthreads();  // all waves done with Ps (aliases Om)

  // O^T lane layout -> Om[q][h] with 4 consecutive h per lane.
  float* OmW = Om + w * 2176;
#pragma unroll
  for (int nt = 0; nt < 4; ++nt)
#pragma unroll
    for (int g = 0; g < 2; ++g)
      *(f32x4*)&OmW[(g * 16 + n) * 68 + nt * 16 + quad * 4] = o[nt][g];
  if (quad == 0) {  // l[q] replicated across quad/i; col q = n.
    Ol[w * 32 + n] = ol[0][0];
    Ol[w * 32 + 16 + n] = ol[1][0];
  }
  __syncthreads();

  // Final combine: 512 threads x 4 floats.
  {
    const int r = tid >> 4;
    const int c0 = (tid & 15) * 4;
    float ax = 0.f, ay = 0.f, az = 0.f, aw = 0.f, ls = 0.f;
#pragma unroll
    for (int ww = 0; ww < 8; ++ww) {
      const float4 vv = *(const float4*)&Om[ww * 2176 + r * 68 + c0];
      ax += vv.x; ay += vv.y; az += vv.z; aw += vv.w;
      ls += Ol[ww * 32 + r];
    }
    const float inv = 1.0f / ls;
    *(float4*)&oB[(size_t)(q0 + r) * HDIM + c0] =
        make_float4(ax * inv, ay * inv, az * inv, aw * inv);
  }
}

extern "C" void kernel_launch(void* const* d_in, const int* in_sizes, int n_in,
                              void* d_out, int out_size, void* d_ws, size_t ws_size,
                              hipStream_t stream) {
  const float* x = (const float*)d_in[0];
  const float* Wq = (const float*)d_in[1];
  const float* Wk = (const float*)d_in[2];
  const float* Wv = (const float*)d_in[3];
  float* out = (float*)d_out;

  ushort_t* wtf = (ushort_t*)d_ws;
  ushort_t* qb = wtf + 3 * 16 * 4 * 512;
  ushort_t* kbf = qb + (size_t)BATCH * SEQT * HDIM;
  ushort_t* vbf = kbf + (size_t)BATCH * 512 * 512;

  convert_w<<<48, 256, 0, stream>>>(Wq, Wk, Wv, wtf);
  qkv_proj<<<BATCH * SEQT / 32, 384, 0, stream>>>(x, wtf, qb, kbf, vbf);
  attn<<<512, 512, 0, stream>>>(qb, kbf, vbf, out);
}

// Round 8
// 111.152 us; speedup vs baseline: 1.3050x; 1.3050x over previous
//
#include <hip/hip_runtime.h>
#include <math.h>

#define BATCH 4
#define SEQT  4096
#define CDIM  512
#define HDIM  64

typedef unsigned short ushort_t;
typedef __attribute__((ext_vector_type(8))) short bf16x8;
typedef __attribute__((ext_vector_type(4))) float f32x4;

#define MFMA16(a, b, c) __builtin_amdgcn_mfma_f32_16x16x32_bf16((a), (b), (c), 0, 0, 0)
#define NEG (-1e30f)

__device__ __forceinline__ ushort_t f2bf(float f) {
  union { float f; unsigned int u; } v;
  v.f = f;
  unsigned int u = v.u;
  u += 0x7fffu + ((u >> 16) & 1u);  // round-to-nearest-even
  return (ushort_t)(u >> 16);
}

// Raw v_exp_f32 (= exp2). log2(e) is folded into the Wq scale so the
// attention softmax needs no per-element multiply before the exp.
__device__ __forceinline__ float fexp2(float x) {
#if __has_builtin(__builtin_amdgcn_exp2f)
  return __builtin_amdgcn_exp2f(x);
#else
  float r;
  asm("v_exp_f32 %0, %1" : "=v"(r) : "v"(x));
  return r;
#endif
}
// Packed f32x2 -> bf16x2 (RNE, lo=arg0 hi=arg1). No builtin on gfx950 -> asm.
__device__ __forceinline__ unsigned int cvtpk(float lo, float hi) {
  unsigned int r;
  asm("v_cvt_pk_bf16_f32 %0, %1, %2" : "=v"(r) : "v"(lo), "v"(hi));
  return r;
}

// ---------------------------------------------------------------------------
// Kernel 0: W[c][h] fp32 -> wtf in MFMA B-fragment order:
//   wtf[((mat*16 + ks)*4 + nt)*512 + lane*8 + j] = W[(ks*32+quad*8+j)*64 + nt*16+n]
// Scale log2(e)/sqrt(512) folded into Wq (attn uses exp2).
// ---------------------------------------------------------------------------
__global__ __launch_bounds__(256) void convert_w(
    const float* __restrict__ Wq, const float* __restrict__ Wk,
    const float* __restrict__ Wv, ushort_t* __restrict__ wtf) {
  int g = blockIdx.x * 256 + threadIdx.x;  // 0 .. 12287
  int lane = g & 63;
  int nt = (g >> 6) & 3;
  int ks = (g >> 8) & 15;
  int mat = g >> 12;
  const float* W = (mat == 0) ? Wq : (mat == 1) ? Wk : Wv;
  // 1/sqrt(512) * log2(e) = 0.06375871540857175
  const float sc = (mat == 0) ? 0.06375871540857175f : 1.0f;
  int n = lane & 15, quad = lane >> 4;
  int h = nt * 16 + n;
  int c0 = ks * 32 + quad * 8;
  ushort_t tmp[8];
#pragma unroll
  for (int j = 0; j < 8; ++j) tmp[j] = f2bf(W[(c0 + j) * HDIM + h] * sc);
  *(bf16x8*)(wtf + (size_t)g * 8) = *(const bf16x8*)tmp;
}

// ---------------------------------------------------------------------------
// Kernel 1: QKV projection. 32 rows/block, 384 threads = 6 waves:
// wave w -> matrix w>>1, row-half w&1. Double-buffered B-frag loads.
// Staging uses v_cvt_pk_bf16_f32 (1 inst / 2 elems, same RNE as f2bf;
// verified passing in R6). Outputs: qb row-major bf16; kbf / vbf in MFMA
// fragment order.
// ---------------------------------------------------------------------------
#define XPAD 520  // shorts; odd-dword stride (260) -> conflict-light

__global__ __launch_bounds__(384) void qkv_proj(
    const float* __restrict__ x, const ushort_t* __restrict__ wtf,
    ushort_t* __restrict__ qb, ushort_t* __restrict__ kbf,
    ushort_t* __restrict__ vbf) {
  __shared__ ushort_t Xs[32 * XPAD];   // 33.3 KB
  __shared__ ushort_t Pk[3][32 * 72];  // 13.8 KB

  const int tid = threadIdx.x;
  const int row0 = blockIdx.x * 32;  // global row = b*4096 + t

  // Stage X tile fp32 -> bf16 (cvt_pk + packed 8B LDS writes).
  const float4* xg = (const float4*)(x + (size_t)row0 * CDIM);
  for (int i = tid; i < 32 * (CDIM / 4); i += 384) {
    float4 xv = xg[i];
    int r = i >> 7, c4 = i & 127;
    uint2 u;
    u.x = cvtpk(xv.x, xv.y);
    u.y = cvtpk(xv.z, xv.w);
    *(uint2*)&Xs[r * XPAD + c4 * 4] = u;
  }
  __syncthreads();

  const int lane = tid & 63;
  const int w = tid >> 6;      // 0..5
  const int mat = w >> 1;      // 0=q 1=k 2=v
  const int half = w & 1;      // row half (16 rows each)
  const int n = lane & 15, quad = lane >> 4;
  const ushort_t* wb = wtf + mat * 32768;

  f32x4 acc[4];
#pragma unroll
  for (int nt = 0; nt < 4; ++nt) acc[nt] = (f32x4){0.f, 0.f, 0.f, 0.f};

  // Software-pipelined B-frag loads (hide L2 latency behind MFMAs).
  bf16x8 bcur[4];
#pragma unroll
  for (int nt = 0; nt < 4; ++nt)
    bcur[nt] = *(const bf16x8*)&wb[nt * 512 + lane * 8];

  for (int ks = 0; ks < 16; ++ks) {
    bf16x8 a = *(const bf16x8*)&Xs[(half * 16 + n) * XPAD + ks * 32 + quad * 8];
    bf16x8 bnext[4];
    if (ks < 15) {
#pragma unroll
      for (int nt = 0; nt < 4; ++nt)
        bnext[nt] = *(const bf16x8*)&wb[((ks + 1) * 4 + nt) * 512 + lane * 8];
    }
#pragma unroll
    for (int nt = 0; nt < 4; ++nt) acc[nt] = MFMA16(a, bcur[nt], acc[nt]);
    if (ks < 15) {
#pragma unroll
      for (int nt = 0; nt < 4; ++nt) bcur[nt] = bnext[nt];
    }
  }

  // C/D -> row-major bf16 in LDS.
  ushort_t* P = Pk[mat];
#pragma unroll
  for (int nt = 0; nt < 4; ++nt)
#pragma unroll
    for (int i = 0; i < 4; ++i)
      P[(half * 16 + quad * 4 + i) * 72 + nt * 16 + n] = f2bf(acc[nt][i]);
  __syncthreads();

  if (mat == 0) {
    // qb rows row0..row0+31; 128 chunks of 32 B over 2 waves.
    int c = half * 64 + lane;
    int r = c >> 2, seg = c & 3;
    const uint4* s = (const uint4*)&Pk[0][r * 72 + seg * 16];
    uint4* d = (uint4*)(qb + (size_t)(row0 + r) * HDIM + seg * 16);
    d[0] = s[0];
    d[1] = s[1];
  } else if (mat == 1) {
    // K fragments: group (row0>>4)+half, frags ks=0,1.
#pragma unroll
    for (int ks2 = 0; ks2 < 2; ++ks2) {
      bf16x8 fr =
          *(const bf16x8*)&Pk[1][(half * 16 + n) * 72 + ks2 * 32 + quad * 8];
      *(bf16x8*)(kbf + (size_t)(((row0 >> 4) + half) * 2 + ks2) * 512 +
                 lane * 8) = fr;
    }
  } else {
    // V^T fragments (in-LDS transpose); wave half emits nt = 2*half, 2*half+1.
    const int b = row0 >> 12, t0 = row0 & 4095;
    const int kt = t0 >> 6, kslot = (t0 >> 5) & 1;
#pragma unroll
    for (int ntc = 0; ntc < 2; ++ntc) {
      const int nt = half * 2 + ntc;
      ushort_t tmp[8];
#pragma unroll
      for (int j = 0; j < 8; ++j)
        tmp[j] = Pk[2][(quad * 8 + j) * 72 + nt * 16 + n];
      *(bf16x8*)(vbf + (size_t)(((b * 64 + kt) * 4 + nt) * 2 + kslot) * 512 +
                 lane * 8) = *(const bf16x8*)tmp;
    }
  }
}

// ---------------------------------------------------------------------------
// Kernel 2: causal flash attention — THE VERIFIED R1 BODY, BYTE-FOR-BYTE
// (111.6us build). FRAGILITY NOTE: every attempt to restructure this
// kernel's blockIdx->qt map or k-loop addressing (R2/R3 hh-loop, R4 hh-loop
// alone, R7 qt-fold + base-ptr hoist) failed with whole-tile output errors
// (absmax ~3-4) that resist source-level auditing. DO NOT change the index
// derivation or load addressing here without a working disasm diff.
// ---------------------------------------------------------------------------
__global__ __launch_bounds__(512, 4) void attn(
    const ushort_t* __restrict__ qb, const ushort_t* __restrict__ kbf,
    const ushort_t* __restrict__ vbf, float* __restrict__ out) {
  // Union: Ps [8][32*72] shorts (36864 B) during k-loop;
  //        Om [8][32*68] floats (69632 B) + Ol [8][32] floats at merge.
  __shared__ __align__(16) char smem[70656];
  ushort_t* Ps = (ushort_t*)smem;
  float* Om = (float*)smem;
  float* Ol = (float*)(smem + 69632);

  const int tid = threadIdx.x;
  const int lane = tid & 63;
  const int w = tid >> 6;  // 0..7
  const int n = lane & 15, quad = lane >> 4;

  const int b = blockIdx.x & 3;
  const int qt = 127 - (blockIdx.x >> 2);  // heavy-first
  const int q0 = qt * 32;

  const ushort_t* qB = qb + (size_t)b * SEQT * HDIM;
  const ushort_t* kB = kbf + (size_t)b * 512 * 512;
  const ushort_t* vB = vbf + (size_t)b * 512 * 512;
  float* oB = out + (size_t)b * SEQT * HDIM;

  // Q fragments, used as the B operand (col = q). Scale folded into Wq.
  bf16x8 qf[2][2];
#pragma unroll
  for (int g = 0; g < 2; ++g)
#pragma unroll
    for (int ks = 0; ks < 2; ++ks)
      qf[g][ks] = *(const bf16x8*)&qB[(size_t)(q0 + g * 16 + n) * HDIM +
                                      ks * 32 + quad * 8];

  bf16x8 ones;
#pragma unroll
  for (int j = 0; j < 8; ++j) ones[j] = (short)0x3F80;  // bf16 1.0

  // o[nt][g] holds O^T: row h = nt*16+quad*4+i, col q = g*16+n.
  f32x4 o[4][2], ol[2];
#pragma unroll
  for (int nt = 0; nt < 4; ++nt)
#pragma unroll
    for (int g = 0; g < 2; ++g) o[nt][g] = (f32x4){0.f, 0.f, 0.f, 0.f};
  ol[0] = (f32x4){0.f, 0.f, 0.f, 0.f};
  ol[1] = (f32x4){0.f, 0.f, 0.f, 0.f};

  const int ktiles = (q0 + 95) >> 6;  // ceil((q0+32)/64)
  ushort_t* Pw = Ps + w * 2304;       // wave-private [q=32][k=64+8pad] u16

  for (int kt = w; kt < ktiles; kt += 8) {
    const int k0 = kt * 64;

    // S^T = K Q^T : C row = k (kk*16+quad*4+i), col = q (g*16+n).
    f32x4 s[4][2];
#pragma unroll
    for (int kk = 0; kk < 4; ++kk) {
      s[kk][0] = (f32x4){0.f, 0.f, 0.f, 0.f};
      s[kk][1] = (f32x4){0.f, 0.f, 0.f, 0.f};
    }
#pragma unroll
    for (int ks = 0; ks < 2; ++ks)
#pragma unroll
      for (int kk = 0; kk < 4; ++kk) {
        bf16x8 kf = *(const bf16x8*)&kB[(size_t)((kt * 4 + kk) * 2 + ks) * 512 +
                                        lane * 8];
        s[kk][0] = MFMA16(kf, qf[0][ks], s[kk][0]);
        s[kk][1] = MFMA16(kf, qf[1][ks], s[kk][1]);
      }

    // Causal mask (diagonal tile only): k-row > q-col.
    if (k0 + 63 > q0) {
#pragma unroll
      for (int kk = 0; kk < 4; ++kk) {
        const int krow = k0 + kk * 16 + quad * 4;
#pragma unroll
        for (int g = 0; g < 2; ++g) {
          const int qcol = q0 + g * 16 + n;
#pragma unroll
          for (int i = 0; i < 4; ++i)
            if (krow + i > qcol) s[kk][g][i] = NEG;
        }
      }
    }

    // p = exp2(s') (max-free; shift cancels in O/l). Each lane holds 4
    // consecutive k for one q-column -> 2 cvt_pk + one b64 LDS write.
#pragma unroll
    for (int kk = 0; kk < 4; ++kk)
#pragma unroll
      for (int g = 0; g < 2; ++g) {
        uint2 wv;
        wv.x = cvtpk(fexp2(s[kk][g][0]), fexp2(s[kk][g][1]));
        wv.y = cvtpk(fexp2(s[kk][g][2]), fexp2(s[kk][g][3]));
        *(uint2*)&Pw[(g * 16 + n) * 72 + kk * 16 + quad * 4] = wv;
      }

    // O^T += V^T P^T ; l += 1^T P^T (wave-private LDS round-trip, no barrier).
    // P^T B-frag = contiguous b128 from row-major Pw[q][k].
#pragma unroll
    for (int ks = 0; ks < 2; ++ks) {
      bf16x8 pb0 = *(const bf16x8*)&Pw[n * 72 + ks * 32 + quad * 8];
      bf16x8 pb1 = *(const bf16x8*)&Pw[(16 + n) * 72 + ks * 32 + quad * 8];
      ol[0] = MFMA16(ones, pb0, ol[0]);
      ol[1] = MFMA16(ones, pb1, ol[1]);
#pragma unroll
      for (int nt = 0; nt < 4; ++nt) {
        bf16x8 vf = *(const bf16x8*)&vB[(size_t)((kt * 4 + nt) * 2 + ks) * 512 +
                                        lane * 8];
        o[nt][0] = MFMA16(vf, pb0, o[nt][0]);
        o[nt][1] = MFMA16(vf, pb1, o[nt][1]);
      }
    }
  }

  // ---- Additive merge of 8 waves. ----
  __syncthreads();  // all waves done with Ps (aliases Om)

  // O^T lane layout -> Om[q][h] with 4 consecutive h per lane.
  float* OmW = Om + w * 2176;
#pragma unroll
  for (int nt = 0; nt < 4; ++nt)
#pragma unroll
    for (int g = 0; g < 2; ++g)
      *(f32x4*)&OmW[(g * 16 + n) * 68 + nt * 16 + quad * 4] = o[nt][g];
  if (quad == 0) {  // l[q] replicated across quad/i; col q = n.
    Ol[w * 32 + n] = ol[0][0];
    Ol[w * 32 + 16 + n] = ol[1][0];
  }
  __syncthreads();

  // Final combine: 512 threads x 4 floats.
  {
    const int r = tid >> 4;
    const int c0 = (tid & 15) * 4;
    float ax = 0.f, ay = 0.f, az = 0.f, aw = 0.f, ls = 0.f;
#pragma unroll
    for (int ww = 0; ww < 8; ++ww) {
      const float4 vv = *(const float4*)&Om[ww * 2176 + r * 68 + c0];
      ax += vv.x; ay += vv.y; az += vv.z; aw += vv.w;
      ls += Ol[ww * 32 + r];
    }
    const float inv = 1.0f / ls;
    *(float4*)&oB[(size_t)(q0 + r) * HDIM + c0] =
        make_float4(ax * inv, ay * inv, az * inv, aw * inv);
  }
}

extern "C" void kernel_launch(void* const* d_in, const int* in_sizes, int n_in,
                              void* d_out, int out_size, void* d_ws, size_t ws_size,
                              hipStream_t stream) {
  const float* x = (const float*)d_in[0];
  const float* Wq = (const float*)d_in[1];
  const float* Wk = (const float*)d_in[2];
  const float* Wv = (const float*)d_in[3];
  float* out = (float*)d_out;

  ushort_t* wtf = (ushort_t*)d_ws;
  ushort_t* qb = wtf + 3 * 16 * 4 * 512;
  ushort_t* kbf = qb + (size_t)BATCH * SEQT * HDIM;
  ushort_t* vbf = kbf + (size_t)BATCH * 512 * 512;

  convert_w<<<48, 256, 0, stream>>>(Wq, Wk, Wv, wtf);
  qkv_proj<<<BATCH * SEQT / 32, 384, 0, stream>>>(x, wtf, qb, kbf, vbf);
  attn<<<512, 512, 0, stream>>>(qb, kbf, vbf, out);
}